// Round 24
// baseline (133.815 us; speedup 1.0000x reference)
//
#include <hip/hip_runtime.h>

// LIF neuron forward, v17: dual-chain asm consumer — vcc-only, no SGPR
// reads, no writelane (the clean ILP test v12/v14 failed to deliver).
// V = leak*V + I; spike = (V >= 1); V -= spike.
// current: [B=8, S=4096, D=1024] f32, membrane: [B, D] f32.
// Outputs concatenated: spikes [B,S,D] then mem_final [B,D], all f32.
//
// Question this kernel decides: is v11's 43cy/step pure dependent-VALU
// latency (4 ops x ~10cy -> floor reached) or ~4-5cy/op latency + ~25cy
// fillable overhead? Two independent channel chains interleaved in one
// asm block: B's ops fill A's gaps; spike bits via v_cndmask(0,1,vcc) +
// v_lshl_add_u32 shift-accumulate in VGPRs (off-chain, hazard-free).
// Skeleton = v11 (72.9us best): 256 blocks, CPB=32, CHUNK=256, NH=16,
// w1 producer distance-1 global_load_lds, w2/w3 writers, raw barriers.
// Masks now channel-major: word per (group g, channel); bit (31-s) =
// step 32g+s. Consumer lanes 0-15 own channel pairs (lx, lx+16).
//
// Numerics (validated r5-r23, absmax 7.6e-6): identical op sequence:
// v = 0.9f*mem + c (mul-then-add, 0x3f666666), f = (v>=1.0),
// mem = f ? v-1 : v. Bit-exact vs numpy fp32 replay.

#define LIF_B 8
#define LIF_S 4096
#define LIF_D 1024
#define CHUNK 256
#define NH    (LIF_S / CHUNK)   // 16
#define CPB   32                // channels per block

typedef __attribute__((address_space(3))) unsigned int lds_uint;
typedef const __attribute__((address_space(1))) unsigned int glb_uint;

// stage one 32KB chunk (256 rows x 32 ch) with 32 x 1KB global_load_lds.
__device__ __forceinline__ void stage_chunk32(const float* gwin, int tb,
                                              int prow, int pcol,
                                              float* slotbase) {
    #pragma unroll
    for (int f = 0; f < CHUNK / 8; ++f) {
        const float* src = gwin + (size_t)(tb + 8 * f + prow) * LIF_D + pcol;
        __builtin_amdgcn_global_load_lds(
            (glb_uint*)(const void*)src,
            (lds_uint*)(void*)(slotbase + (size_t)f * 256), 16, 0, 0);
    }
}

// One global time step for two independent channel chains, interleaved.
// vcc-only; masks shift-accumulate in VGPRs (bit 31-s = step s of group).
__device__ __forceinline__ void lif_step2(float cA, float cB,
                                          float& memA, float& memB,
                                          unsigned& mkA, unsigned& mkB) {
    float vA, vB, wA, wB;
    unsigned bA, bB;
    asm volatile(
        "v_mul_f32 %[va], 0x3f666666, %[ma]\n\t"    // vA = 0.9*memA
        "v_mul_f32 %[vb], 0x3f666666, %[mb]\n\t"    // vB = 0.9*memB
        "v_add_f32 %[va], %[va], %[ca]\n\t"         // vA += cA
        "v_add_f32 %[vb], %[vb], %[cb]\n\t"         // vB += cB
        "v_cmp_ge_f32 vcc, %[va], 1.0\n\t"          // fA
        "v_add_f32 %[wa], -1.0, %[va]\n\t"          // wA (gap filler)
        "v_add_f32 %[wb], -1.0, %[vb]\n\t"          // wB (gap filler)
        "v_cndmask_b32 %[ma], %[va], %[wa], vcc\n\t"// memA = fA ? wA : vA
        "v_cndmask_b32 %[ba], 0, 1, vcc\n\t"        // bA = fA (VOP3 inline)
        "v_cmp_ge_f32 vcc, %[vb], 1.0\n\t"          // fB
        "v_lshl_add_u32 %[mka], %[mka], 1, %[ba]\n\t" // mkA = mkA<<1 | bA
        "v_cndmask_b32 %[mb], %[vb], %[wb], vcc\n\t"// memB = fB ? wB : vB
        "v_cndmask_b32 %[bb], 0, 1, vcc\n\t"        // bB = fB
        "v_lshl_add_u32 %[mkb], %[mkb], 1, %[bb]"   // mkB = mkB<<1 | bB
        : [va]"=&v"(vA), [vb]"=&v"(vB), [wa]"=&v"(wA), [wb]"=&v"(wB),
          [ba]"=&v"(bA), [bb]"=&v"(bB),
          [ma]"+v"(memA), [mb]"+v"(memB),
          [mka]"+v"(mkA), [mkb]"+v"(mkB)
        : [ca]"v"(cA), [cb]"v"(cB)
        : "vcc");
}

#define STEP16(PA_, PB_) do { \
    lif_step2(PA_[ 0], PB_[ 0], memA, memB, mkA, mkB); \
    lif_step2(PA_[ 1], PB_[ 1], memA, memB, mkA, mkB); \
    lif_step2(PA_[ 2], PB_[ 2], memA, memB, mkA, mkB); \
    lif_step2(PA_[ 3], PB_[ 3], memA, memB, mkA, mkB); \
    lif_step2(PA_[ 4], PB_[ 4], memA, memB, mkA, mkB); \
    lif_step2(PA_[ 5], PB_[ 5], memA, memB, mkA, mkB); \
    lif_step2(PA_[ 6], PB_[ 6], memA, memB, mkA, mkB); \
    lif_step2(PA_[ 7], PB_[ 7], memA, memB, mkA, mkB); \
    lif_step2(PA_[ 8], PB_[ 8], memA, memB, mkA, mkB); \
    lif_step2(PA_[ 9], PB_[ 9], memA, memB, mkA, mkB); \
    lif_step2(PA_[10], PB_[10], memA, memB, mkA, mkB); \
    lif_step2(PA_[11], PB_[11], memA, memB, mkA, mkB); \
    lif_step2(PA_[12], PB_[12], memA, memB, mkA, mkB); \
    lif_step2(PA_[13], PB_[13], memA, memB, mkA, mkB); \
    lif_step2(PA_[14], PB_[14], memA, memB, mkA, mkB); \
    lif_step2(PA_[15], PB_[15], memA, memB, mkA, mkB); \
} while (0)

__global__ __launch_bounds__(256, 1) void lif_v17_kernel(
    const float* __restrict__ current,
    const float* __restrict__ membrane,
    float* __restrict__ spikes,
    float* __restrict__ mem_out)
{
    #pragma clang fp contract(off)

    __shared__ __align__(16) float in_ring[2][CHUNK][CPB];   // 64 KB
    __shared__ unsigned mask_lds[2][8][CPB];                 // 2 KB, channel-major

    const int wid  = threadIdx.x >> 6;   // 0=consumer 1=producer 2,3=writers
    const int lane = threadIdx.x & 63;
    const int blk  = blockIdx.x;         // 0..255
    const int bb   = blk >> 5;           // batch (1024/32 = 32 ch-blocks)
    const int ch0  = (blk & 31) * CPB;

    const float* gwin  = current + (size_t)bb * LIF_S * LIF_D + ch0;
    float*       sbase = spikes  + (size_t)bb * LIF_S * LIF_D + ch0;

    const int prow = lane >> 3;          // producer 8-row mapping
    const int pcol = (lane & 7) * 4;
    const int lx   = lane & 15;          // chain A ch = lx, chain B ch = lx+16

    float memA = 0.0f, memB = 0.0f;

    // ---- prologue: producer stages chunk 0; consumer loads membrane ----
    if (wid == 1) {
        stage_chunk32(gwin, 0, prow, pcol, &in_ring[0][0][0]);
        asm volatile("s_waitcnt vmcnt(0)" ::: "memory");
    } else if (wid == 0 && lane < 16) {
        memA = membrane[bb * LIF_D + ch0 + lx];
        memB = membrane[bb * LIF_D + ch0 + 16 + lx];
    }
    __builtin_amdgcn_s_barrier();
    asm volatile("" ::: "memory");

    for (int h = 0; h < NH; ++h) {
        if (wid == 0) {
            // ---- consumer: 256 steps, 2 chains/lane, 8 mask groups ----
            const float* ib = &in_ring[h & 1][0][lx];
            float PA[16], PBv[16], QA[16], QB[16];
            #pragma unroll
            for (int j = 0; j < 16; ++j) { PA[j] = ib[j * CPB];
                                           PBv[j] = ib[j * CPB + 16]; }
            #pragma unroll
            for (int j = 0; j < 16; ++j) { QA[j] = ib[(16 + j) * CPB];
                                           QB[j] = ib[(16 + j) * CPB + 16]; }
            unsigned mkA = 0u, mkB = 0u;

            #pragma unroll
            for (int g = 0; g < 8; ++g) {
                STEP16(PA, PBv);                  // steps 32g+0..15
                if (g < 7) {
                    #pragma unroll
                    for (int j = 0; j < 16; ++j) {
                        PA[j]  = ib[(32 * g + 32 + j) * CPB];
                        PBv[j] = ib[(32 * g + 32 + j) * CPB + 16];
                    }
                }
                STEP16(QA, QB);                   // steps 32g+16..31
                if (lane < 16) {
                    mask_lds[h & 1][g][lx]      = mkA;   // ch lx
                    mask_lds[h & 1][g][16 + lx] = mkB;   // ch lx+16
                }
                mkA = 0u; mkB = 0u;
                if (g < 7) {
                    #pragma unroll
                    for (int j = 0; j < 16; ++j) {
                        QA[j] = ib[(32 * g + 48 + j) * CPB];
                        QB[j] = ib[(32 * g + 48 + j) * CPB + 16];
                    }
                }
            }
            asm volatile("s_waitcnt lgkmcnt(0)" ::: "memory");
        } else if (wid == 1) {
            // ---- producer: stage chunk h+1 into the other slot ----
            if (h + 1 < NH) {
                stage_chunk32(gwin, (h + 1) * CHUNK, prow, pcol,
                              &in_ring[(h + 1) & 1][0][0]);
                asm volatile("s_waitcnt vmcnt(0)" ::: "memory");
            }
        } else {
            // ---- writers: expand channel-major masks of phase h-1 ----
            if (h >= 1) {
                const int ph = (h - 1) & 1;
                const int tb = (h - 1) * CHUNK;
                const int rbase = (wid == 3) ? 128 : 0;
                const int chb   = lane & 31;      // channel
                const int rhalf = lane >> 5;      // 0/1
                #pragma unroll 8
                for (int k = 0; k < 64; ++k) {
                    const int row = rbase + 2 * k + rhalf;         // local row
                    const unsigned m = mask_lds[ph][row >> 5][chb];
                    const float sv = (float)((m >> (31 - (row & 31))) & 1u);
                    sbase[(size_t)(tb + row) * LIF_D + chb] = sv;
                }
                asm volatile("s_waitcnt lgkmcnt(0)" ::: "memory");
            }
        }
        __builtin_amdgcn_s_barrier();
        asm volatile("" ::: "memory");
    }

    // ---- epilogue: flush masks of phase NH-1; store final membrane ----
    if (wid >= 2) {
        const int ph = (NH - 1) & 1;
        const int tb = (NH - 1) * CHUNK;
        const int rbase = (wid == 3) ? 128 : 0;
        const int chb   = lane & 31;
        const int rhalf = lane >> 5;
        #pragma unroll 8
        for (int k = 0; k < 64; ++k) {
            const int row = rbase + 2 * k + rhalf;
            const unsigned m = mask_lds[ph][row >> 5][chb];
            const float sv = (float)((m >> (31 - (row & 31))) & 1u);
            sbase[(size_t)(tb + row) * LIF_D + chb] = sv;
        }
    } else if (wid == 0 && lane < 16) {
        mem_out[bb * LIF_D + ch0 + lx]      = memA;
        mem_out[bb * LIF_D + ch0 + 16 + lx] = memB;
    }
}

extern "C" void kernel_launch(void* const* d_in, const int* in_sizes, int n_in,
                              void* d_out, int out_size, void* d_ws, size_t ws_size,
                              hipStream_t stream) {
    const float* current  = (const float*)d_in[0];   // [8, 4096, 1024]
    const float* membrane = (const float*)d_in[1];   // [8, 1024]

    float* spikes  = (float*)d_out;                                 // [8,4096,1024]
    float* mem_out = (float*)d_out + (size_t)LIF_B * LIF_S * LIF_D; // [8,1024]

    dim3 block(256);                   // w0 consumer, w1 producer, w2-3 writers
    dim3 grid(LIF_B * LIF_D / CPB);    // 256 blocks (32 channels each)

    hipLaunchKernelGGL(lif_v17_kernel, grid, block, 0, stream,
                       current, membrane, spikes, mem_out);
}